// Round 9
// baseline (360.529 us; speedup 1.0000x reference)
//
#include <hip/hip_runtime.h>

#define HDIM 768
#define BM 64                 // rows per block
#define NCHUNK 24             // K chunks of 32
#define SLAB_B 16384          // bytes per B slab: 256 cols x 64B (32 k halves)
#define A_STRIDE 1552         // bytes per A row in LDS (768 halves + 8 pad)

typedef _Float16 f16x8 __attribute__((ext_vector_type(8)));
typedef _Float16 f16x2 __attribute__((ext_vector_type(2)));
typedef float f32x4 __attribute__((ext_vector_type(4)));
typedef float f32x2 __attribute__((ext_vector_type(2)));

// ---- LDS layout (bytes), dynamic: 158976 <= 163840 ----
#define LDS_A     0            // A resident: [64][1552B] = 99328
#define LDS_B     99328        // B slab ring: 3 x 16384 = 49152
#define LDS_BIAS  148480       // 768 f32
#define LDS_V     151552       // 768 f32
#define LDS_SRED  154624       // [16][64] f32 = 4096
#define LDS_E     158720       // 64 f32
#define LDS_TOTAL 158976

// ---- workspace layout (bytes) ----
#define WS_WT    0             // 768*768*2 = 1179648 (fp16 W, chunked+swizzled)
#define WS_Z     1179648       // 4 (+pad)
#define WS_PART  1179712       // 2048*768*4 = 6291456
#define WS_PART2 7471168       // 16*768*4 = 49152
#define WS_NEED  (WS_PART2 + 49152)

__device__ __forceinline__ float tanh_fast(float z) {
    float e2 = __expf(2.0f * z);
    return 1.0f - 2.0f / (e2 + 1.0f);   // inf-safe at both extremes
}

__device__ __forceinline__ void stage16(const void* g, void* l) {
    __builtin_amdgcn_global_load_lds(
        (const __attribute__((address_space(1))) void*)g,
        (__attribute__((address_space(3))) void*)l, 16, 0, 0);
}

__device__ __forceinline__ f16x8 cvt8(f32x4 x0, f32x4 x1) {
    f16x8 f;
    f[0] = (_Float16)x0[0]; f[1] = (_Float16)x0[1];
    f[2] = (_Float16)x0[2]; f[3] = (_Float16)x0[3];
    f[4] = (_Float16)x1[0]; f[5] = (_Float16)x1[1];
    f[6] = (_Float16)x1[2]; f[7] = (_Float16)x1[3];
    return f;
}

// ---------------- kernel 1: W -> fp16 chunks [kc][col][32k], 16B-quad XOR-swizzled ----------------
// quad position for k-quarter q of col c: q ^ ((c>>1)&3). Verified round 7: staging is a
// linear copy, score reads with the same XOR -> 0 LDS bank conflicts on B.
__global__ __launch_bounds__(1024) void prep_kernel(
    const float* __restrict__ W, _Float16* __restrict__ Wt,
    float* __restrict__ Z, float* __restrict__ accbuf) {
    int idx = blockIdx.x * 1024 + threadIdx.x;      // 73728 quads (768 cols * 24 kc * 4 q)
    if (idx < 73728) {
        int c  = idx / 96;
        int r  = idx - c * 96;
        int kc = r >> 2;
        int q  = r & 3;
        const float* src = W + c * HDIM + kc * 32 + q * 8;
        f32x4 x0 = *(const f32x4*)src;
        f32x4 x1 = *(const f32x4*)(src + 4);
        f16x8 v = cvt8(x0, x1);
        int qs = q ^ ((c >> 1) & 3);
        *(f16x8*)((char*)Wt + (size_t)kc * (3 * SLAB_B) + c * 64 + qs * 16) = v;
    }
    if (idx < HDIM) accbuf[idx] = 0.0f;
    if (idx == 0) *Z = 0.0f;
}

// ---------------- kernel 2: fused GEMM + tanh + v-dot + exp + weighted sum ----------------
// 1024 threads (16 waves), BM=64, grid 2048, 1 block/CU (155KB LDS).
// A resident fp16 in LDS; B in a 3-slab ring (256 cols each), staged 2 phases ahead via
// global_load_lds. Per phase: read frags -> issue stage(g+2) -> lgkmcnt(0)+sched_barrier
// -> 4 MFMAs -> s_waitcnt vmcnt(1) -> raw s_barrier (counted waits: never drain to 0).
// Invariant: slab g+1's stage is >=2-old at the end-of-phase vmcnt(1) (stage g+2 newer),
// so it is landed before any wave crosses the barrier.
__global__ __launch_bounds__(1024, 4) void score_fused_kernel(
    const float* __restrict__ h, const _Float16* __restrict__ Wt,
    const float* __restrict__ bias, const float* __restrict__ vvec,
    float* __restrict__ part, float* __restrict__ accbuf,
    float* __restrict__ Z, int use_part) {

    extern __shared__ char smem[];
    float* bias_s = (float*)(smem + LDS_BIAS);
    float* v_s    = (float*)(smem + LDS_V);
    float* s_red  = (float*)(smem + LDS_SRED);
    float* e_lds  = (float*)(smem + LDS_E);

    const int tid  = threadIdx.x;
    const int wave = tid >> 6;       // = col-group 0..15
    const int lane = tid & 63;
    const int l15  = lane & 15;
    const int lhi  = lane >> 4;
    const int row0 = blockIdx.x * BM;

    if (tid < HDIM) { bias_s[tid] = bias[tid]; v_s[tid] = vvec[tid]; }

    // B-frag read offset inside a slab: local col = wave*16 + l15 (tile p*16+wave),
    // quad XOR matches prep's swizzle (col multiple-of-16 terms drop out of (c>>1)&3).
    const int quad = lhi ^ ((l15 >> 1) & 3);
    const int boff = (wave * 16 + l15) * 64 + quad * 16;

    // prologue: stage slabs 0,1 into ring bufs 0,1 (1 gload/thread each, linear)
    stage16((const char*)Wt + tid * 16,          smem + LDS_B + 0 * SLAB_B + tid * 16);
    stage16((const char*)Wt + SLAB_B + tid * 16, smem + LDS_B + 1 * SLAB_B + tid * 16);
    // prologue: A slice 0 (64 rows x 32k): thread -> (row tid>>4, half-pair tid&15)
    {
        f32x2 a0 = *(const f32x2*)(h + (size_t)(row0 + (tid >> 4)) * HDIM + (tid & 15) * 2);
        f16x2 h2; h2[0] = (_Float16)a0[0]; h2[1] = (_Float16)a0[1];
        *(f16x2*)(smem + LDS_A + (tid >> 4) * A_STRIDE + (tid & 15) * 4) = h2;
    }
    __syncthreads();   // full drain once: slabs 0,1 + A0 + bias/v ready

    f32x4 acc[4][3];
    #pragma unroll
    for (int rt = 0; rt < 4; ++rt)
        #pragma unroll
        for (int ct = 0; ct < 3; ++ct)
            acc[rt][ct] = (f32x4){0.f, 0.f, 0.f, 0.f};

    #pragma unroll 1
    for (int kc = 0; kc < NCHUNK; ++kc) {
        f16x8 af0, af1, af2, af3;
        f32x2 pa;
        // ---------- phase 0: compute slab 3kc (buf0); stage slab 3kc+2 -> buf2 ----------
        {
            f16x8 bfr = *(const f16x8*)(smem + LDS_B + 0 * SLAB_B + boff);
            const char* ab = smem + LDS_A + l15 * A_STRIDE + kc * 64 + lhi * 16;
            af0 = *(const f16x8*)(ab);
            af1 = *(const f16x8*)(ab + 16 * A_STRIDE);
            af2 = *(const f16x8*)(ab + 32 * A_STRIDE);
            af3 = *(const f16x8*)(ab + 48 * A_STRIDE);
            stage16((const char*)Wt + (size_t)(3 * kc + 2) * SLAB_B + tid * 16,
                    smem + LDS_B + 2 * SLAB_B + tid * 16);
            int ka = (kc + 1 < NCHUNK) ? kc + 1 : kc;   // clamp keeps issue count uniform
            pa = *(const f32x2*)(h + (size_t)(row0 + (tid >> 4)) * HDIM + ka * 32 + (tid & 15) * 2);
            asm volatile("s_waitcnt lgkmcnt(0)" ::: "memory");
            __builtin_amdgcn_sched_barrier(0);
            acc[0][0] = __builtin_amdgcn_mfma_f32_16x16x32_f16(af0, bfr, acc[0][0], 0, 0, 0);
            acc[1][0] = __builtin_amdgcn_mfma_f32_16x16x32_f16(af1, bfr, acc[1][0], 0, 0, 0);
            acc[2][0] = __builtin_amdgcn_mfma_f32_16x16x32_f16(af2, bfr, acc[2][0], 0, 0, 0);
            acc[3][0] = __builtin_amdgcn_mfma_f32_16x16x32_f16(af3, bfr, acc[3][0], 0, 0, 0);
            asm volatile("s_waitcnt vmcnt(1)" ::: "memory");
            __builtin_amdgcn_s_barrier();
        }
        // ---------- phase 1: compute slab 3kc+1 (buf1); stage slab 3kc+3 -> buf0 ----------
        {
            f16x8 bfr = *(const f16x8*)(smem + LDS_B + 1 * SLAB_B + boff);
            int sg = 3 * kc + 3; if (sg > 71) sg = 71;   // clamped dummy keeps counts uniform
            stage16((const char*)Wt + (size_t)sg * SLAB_B + tid * 16,
                    smem + LDS_B + 0 * SLAB_B + tid * 16);
            asm volatile("s_waitcnt lgkmcnt(0)" ::: "memory");
            __builtin_amdgcn_sched_barrier(0);
            acc[0][1] = __builtin_amdgcn_mfma_f32_16x16x32_f16(af0, bfr, acc[0][1], 0, 0, 0);
            acc[1][1] = __builtin_amdgcn_mfma_f32_16x16x32_f16(af1, bfr, acc[1][1], 0, 0, 0);
            acc[2][1] = __builtin_amdgcn_mfma_f32_16x16x32_f16(af2, bfr, acc[2][1], 0, 0, 0);
            acc[3][1] = __builtin_amdgcn_mfma_f32_16x16x32_f16(af3, bfr, acc[3][1], 0, 0, 0);
            asm volatile("s_waitcnt vmcnt(1)" ::: "memory");
            __builtin_amdgcn_s_barrier();
        }
        // ---------- phase 2: compute slab 3kc+2 (buf2); stage slab 3kc+4 -> buf1; A write ----------
        {
            f16x8 bfr = *(const f16x8*)(smem + LDS_B + 2 * SLAB_B + boff);
            int sg = 3 * kc + 4; if (sg > 71) sg = 71;
            stage16((const char*)Wt + (size_t)sg * SLAB_B + tid * 16,
                    smem + LDS_B + 1 * SLAB_B + tid * 16);
            asm volatile("s_waitcnt lgkmcnt(0)" ::: "memory");
            __builtin_amdgcn_sched_barrier(0);
            acc[0][2] = __builtin_amdgcn_mfma_f32_16x16x32_f16(af0, bfr, acc[0][2], 0, 0, 0);
            acc[1][2] = __builtin_amdgcn_mfma_f32_16x16x32_f16(af1, bfr, acc[1][2], 0, 0, 0);
            acc[2][2] = __builtin_amdgcn_mfma_f32_16x16x32_f16(af2, bfr, acc[2][2], 0, 0, 0);
            acc[3][2] = __builtin_amdgcn_mfma_f32_16x16x32_f16(af3, bfr, acc[3][2], 0, 0, 0);
            if (kc + 1 < NCHUNK) {   // write next A slice (pa use: compiler inserts vmcnt wait)
                f16x2 h2; h2[0] = (_Float16)pa[0]; h2[1] = (_Float16)pa[1];
                *(f16x2*)(smem + LDS_A + (tid >> 4) * A_STRIDE + (kc + 1) * 64
                          + (tid & 15) * 4) = h2;
            }
            asm volatile("s_waitcnt lgkmcnt(0)" ::: "memory");   // A write landed
            asm volatile("s_waitcnt vmcnt(1)" ::: "memory");     // slab 3kc+3 landed
            __builtin_amdgcn_s_barrier();
        }
    }
    __syncthreads();   // drain clamped dummy stages + pa before epilogue

    // ---- epilogue: per-wave col-partial scores (col = ct*256 + wave*16 + l15) ----
    float pr[4][4];
    #pragma unroll
    for (int rt = 0; rt < 4; ++rt)
        #pragma unroll
        for (int r = 0; r < 4; ++r) pr[rt][r] = 0.f;

    #pragma unroll
    for (int ct = 0; ct < 3; ++ct) {
        int col = ct * 256 + wave * 16 + l15;
        float bj = bias_s[col];
        float vj = v_s[col];
        #pragma unroll
        for (int rt = 0; rt < 4; ++rt)
            #pragma unroll
            for (int r = 0; r < 4; ++r)
                pr[rt][r] = fmaf(vj, tanh_fast(acc[rt][ct][r] + bj), pr[rt][r]);
    }
    #pragma unroll
    for (int rt = 0; rt < 4; ++rt)
        #pragma unroll
        for (int r = 0; r < 4; ++r) {
            float x = pr[rt][r];
            x += __shfl_xor(x, 1);
            x += __shfl_xor(x, 2);
            x += __shfl_xor(x, 4);
            x += __shfl_xor(x, 8);
            if (l15 == 0) s_red[wave * 64 + rt * 16 + lhi * 4 + r] = x;
        }
    __syncthreads();

    // rows: sum 16 col-group partials, exp, block Z
    if (tid < 64) {
        float s = 0.f;
        #pragma unroll
        for (int w = 0; w < 16; ++w) s += s_red[w * 64 + tid];
        float e = __expf(s);            // |s| <= ||v||_1 ~ 61: no overflow
        e_lds[tid] = e;
        float tot = e;
        tot += __shfl_xor(tot, 1);
        tot += __shfl_xor(tot, 2);
        tot += __shfl_xor(tot, 4);
        tot += __shfl_xor(tot, 8);
        tot += __shfl_xor(tot, 16);
        tot += __shfl_xor(tot, 32);
        if (tid == 0) atomicAdd(Z, tot);
    }
    __syncthreads();

    // ---- fused weighted sum from resident A (h read from HBM exactly once) ----
    if (tid < HDIM) {
        const _Float16* A = (const _Float16*)(smem + LDS_A);
        float s = 0.f;
        #pragma unroll 8
        for (int i = 0; i < BM; ++i)
            s += e_lds[i] * (float)A[i * (A_STRIDE / 2) + tid];
        if (use_part) part[(size_t)blockIdx.x * HDIM + tid] = s;
        else          atomicAdd(accbuf + tid, s);
    }
}

// ---------------- finalize stage 1: sum 2048 parts in 16 groups of 128 ----------------
__global__ __launch_bounds__(128) void fin1_kernel(
    const float* __restrict__ part, float* __restrict__ part2) {
    const int g  = blockIdx.x / 6;           // group 0..15
    const int cb = blockIdx.x % 6;
    const int col = cb * 128 + threadIdx.x;
    float s = 0.f;
    #pragma unroll 8
    for (int p = g * 128; p < (g + 1) * 128; ++p) s += part[(size_t)p * HDIM + col];
    part2[g * HDIM + col] = s;
}

// ---------------- finalize stage 2: out[j] = sum_g src[g][j] / Z ----------------
__global__ __launch_bounds__(128) void fin2_kernel(
    const float* __restrict__ src, const float* __restrict__ Z,
    float* __restrict__ out, int ngroups) {
    const int col = blockIdx.x * 128 + threadIdx.x;
    float s = 0.f;
    for (int g = 0; g < ngroups; ++g) s += src[g * HDIM + col];
    out[col] = s / (*Z);
}

extern "C" void kernel_launch(void* const* d_in, const int* in_sizes, int n_in,
                              void* d_out, int out_size, void* d_ws, size_t ws_size,
                              hipStream_t stream) {
    const float* h    = (const float*)d_in[0];   // [N, 768]
    const float* W    = (const float*)d_in[1];   // [768, 768]
    const float* bias = (const float*)d_in[2];   // [768]
    const float* vv   = (const float*)d_in[3];   // [1, 768]
    float* out = (float*)d_out;                  // [1, 768] fp32

    const int n = in_sizes[0] / HDIM;            // 131072

    char* ws = (char*)d_ws;
    _Float16* Wt  = (_Float16*)(ws + WS_WT);
    float* Z      = (float*)(ws + WS_Z);
    float* part   = (float*)(ws + WS_PART);
    float* part2  = (float*)(ws + WS_PART2);
    float* accbuf = (float*)(ws + WS_PART);      // small-ws fallback accumulator

    const int use_part = (ws_size >= (size_t)WS_NEED) ? 1 : 0;

    hipFuncSetAttribute((const void*)score_fused_kernel,
                        hipFuncAttributeMaxDynamicSharedMemorySize, LDS_TOTAL);

    // 1) W -> fp16 swizzled chunks; zero Z (+acc)
    prep_kernel<<<72, 1024, 0, stream>>>(W, Wt, Z, accbuf);

    // 2) fused score + exp + weighted-sum partials
    score_fused_kernel<<<n / BM, 1024, LDS_TOTAL, stream>>>(
        h, Wt, bias, vv, part, accbuf, Z, use_part);

    // 3) reduce partials
    if (use_part) {
        fin1_kernel<<<96, 128, 0, stream>>>(part, part2);
        fin2_kernel<<<HDIM / 128, 128, 0, stream>>>(part2, Z, out, 16);
    } else {
        fin2_kernel<<<HDIM / 128, 128, 0, stream>>>(accbuf, Z, out, 1);
    }
}

// Round 10
// 328.715 us; speedup vs baseline: 1.0968x; 1.0968x over previous
//
#include <hip/hip_runtime.h>

#define HDIM 768
#define BM 64                 // rows per block
#define NCHUNK 24             // K chunks of 32
#define CHUNK_B 49152         // bytes per Wt chunk: 768 cols x 64B (32 k halves)
#define A_STRIDE 1536         // bytes per A row in LDS (multiple of 128B: row term drops from bank index)
// A swizzle: byte offset within a row is XORed with ((row&7)<<4) — 16B-slot involution.
// Read: 16 l15-lanes spread over 8 start banks x2 = 2-way (free, m136). Applied on BOTH
// write and read sides (rule 21).
#define ASWZ(row) (((row) & 7) << 4)

typedef _Float16 f16x8 __attribute__((ext_vector_type(8)));
typedef _Float16 f16x4 __attribute__((ext_vector_type(4)));
typedef float f32x4 __attribute__((ext_vector_type(4)));

// ---- LDS layout (bytes), dynamic: 157952 <= 163840 ----
#define LDS_A     0            // A resident: [64][1536B] = 98304
#define LDS_BB    98304        // B chunk (single buffer): 49152
#define LDS_BIAS  147456       // 768 f32
#define LDS_V     150528       // 768 f32
#define LDS_SRED  153600       // [16][64] f32 = 4096
#define LDS_E     157696       // 64 f32
#define LDS_TOTAL 157952

// ---- workspace layout (bytes) ----
#define WS_WT    0             // 768*768*2 = 1179648 (fp16 W, chunked+swizzled)
#define WS_Z     1179648       // 4 (+pad)
#define WS_PART  1179712       // 2048*768*4 = 6291456
#define WS_PART2 7471168       // 16*768*4 = 49152
#define WS_NEED  (WS_PART2 + 49152)

__device__ __forceinline__ float tanh_fast(float z) {
    float e2 = __expf(2.0f * z);
    return 1.0f - 2.0f / (e2 + 1.0f);   // inf-safe at both extremes
}

__device__ __forceinline__ void stage16(const void* g, void* l) {
    __builtin_amdgcn_global_load_lds(
        (const __attribute__((address_space(1))) void*)g,
        (__attribute__((address_space(3))) void*)l, 16, 0, 0);
}

__device__ __forceinline__ f16x8 cvt8(f32x4 x0, f32x4 x1) {
    f16x8 f;
    f[0] = (_Float16)x0[0]; f[1] = (_Float16)x0[1];
    f[2] = (_Float16)x0[2]; f[3] = (_Float16)x0[3];
    f[4] = (_Float16)x1[0]; f[5] = (_Float16)x1[1];
    f[6] = (_Float16)x1[2]; f[7] = (_Float16)x1[3];
    return f;
}

// ---------------- kernel 1: W -> fp16 chunks [kc][col][32k], 16B-quad XOR-swizzled ----------------
// quad position for k-quarter q of col c: q ^ ((c>>1)&3). Verified round 7: staging is a
// linear copy, score reads with the same XOR -> 0 LDS bank conflicts on B.
__global__ __launch_bounds__(1024) void prep_kernel(
    const float* __restrict__ W, _Float16* __restrict__ Wt,
    float* __restrict__ Z, float* __restrict__ accbuf) {
    int idx = blockIdx.x * 1024 + threadIdx.x;      // 73728 quads (768 cols * 24 kc * 4 q)
    if (idx < 73728) {
        int c  = idx / 96;
        int r  = idx - c * 96;
        int kc = r >> 2;
        int q  = r & 3;
        const float* src = W + c * HDIM + kc * 32 + q * 8;
        f32x4 x0 = *(const f32x4*)src;
        f32x4 x1 = *(const f32x4*)(src + 4);
        f16x8 v = cvt8(x0, x1);
        int qs = q ^ ((c >> 1) & 3);
        *(f16x8*)((char*)Wt + (size_t)kc * CHUNK_B + c * 64 + qs * 16) = v;
    }
    if (idx < HDIM) accbuf[idx] = 0.0f;
    if (idx == 0) *Z = 0.0f;
}

// ---------------- kernel 2: fused GEMM + tanh + v-dot + exp + weighted sum ----------------
// 1024 threads (16 waves), BM=64 rows, grid 2048, 1 block/CU (154KB LDS).
// A resident in LDS fp16, XOR-swizzled (this round's change: kills the 8-way A-read
// bank conflict that capped rounds 8-9). B single-buffer staged via global_load_lds
// from pre-swizzled Wt (L2-hot, 0-conflict reads).
// Wave w owns cols [w*48, w*48+48): 4 row-tiles x 3 col-tiles, acc[4][3]=48 VGPR.
__global__ __launch_bounds__(1024, 4) void score_fused_kernel(
    const float* __restrict__ h, const _Float16* __restrict__ Wt,
    const float* __restrict__ bias, const float* __restrict__ vvec,
    float* __restrict__ part, float* __restrict__ accbuf,
    float* __restrict__ Z, int use_part) {

    extern __shared__ char smem[];
    float* bias_s = (float*)(smem + LDS_BIAS);
    float* v_s    = (float*)(smem + LDS_V);
    float* s_red  = (float*)(smem + LDS_SRED);
    float* e_lds  = (float*)(smem + LDS_E);

    const int tid  = threadIdx.x;
    const int wave = tid >> 6;       // = col-group 0..15
    const int lane = tid & 63;
    const int l15  = lane & 15;
    const int lhi  = lane >> 4;
    const int row0 = blockIdx.x * BM;

    if (tid < HDIM) { bias_s[tid] = bias[tid]; v_s[tid] = vvec[tid]; }

    // loop-invariant B-read offset (round-7 verified swizzle):
    // col = wave*48 + ct*16 + l15; (col>>1)&3 == (l15>>1)&3 since wave*48, ct*16 are mult of 8
    const int quad = lhi ^ ((l15 >> 1) & 3);
    const int boff = (wave * 48 + l15) * 64 + quad * 16;

    // prologue: stage B chunk 0 (48 x 1KB wave-instructions, linear copy)
    #pragma unroll
    for (int s = 0; s < 3; ++s) {
        int idx = wave * 3 + s;
        stage16((const char*)Wt + idx * 1024 + lane * 16, smem + LDS_BB + idx * 1024);
    }
    // prologue: A slice 0 (64 rows x 32 k fp32 -> fp16), swizzled write
    if (tid < 512) {
        int r = tid >> 3, k4 = tid & 7;
        f32x4 x = *(const f32x4*)(h + (size_t)(row0 + r) * HDIM + k4 * 4);
        f16x4 v;
        v[0] = (_Float16)x[0]; v[1] = (_Float16)x[1];
        v[2] = (_Float16)x[2]; v[3] = (_Float16)x[3];
        *(f16x4*)(smem + LDS_A + r * A_STRIDE + ((k4 * 8) ^ ASWZ(r))) = v;
    }
    __syncthreads();

    f32x4 acc[4][3];
    #pragma unroll
    for (int rt = 0; rt < 4; ++rt)
        #pragma unroll
        for (int ct = 0; ct < 3; ++ct)
            acc[rt][ct] = (f32x4){0.f, 0.f, 0.f, 0.f};

    // per-lane A-read swizzle: rows l15, l15+16, +32, +48 all have row&7 == l15&7
    const int aswz = ASWZ(l15);

    for (int kc = 0; kc < NCHUNK; ++kc) {
        const bool has = (kc + 1 < NCHUNK);
        // T14 issue-early: next A slice global loads (drained by barrier1, ~full compute later)
        f32x4 pa;
        if (has && tid < 512)
            pa = *(const f32x4*)(h + (size_t)(row0 + (tid >> 3)) * HDIM
                                   + (kc + 1) * 32 + (tid & 7) * 4);

        // compute chunk kc: 7 ds_read_b128 -> 12 MFMAs
        const char* bb = smem + LDS_BB + boff;
        f16x8 b0 = *(const f16x8*)(bb);
        f16x8 b1 = *(const f16x8*)(bb + 1024);
        f16x8 b2 = *(const f16x8*)(bb + 2048);
        const char* ab = smem + LDS_A + l15 * A_STRIDE + ((kc * 64 + lhi * 16) ^ aswz);
        f16x8 a0 = *(const f16x8*)(ab);
        f16x8 a1 = *(const f16x8*)(ab + 16 * A_STRIDE);
        f16x8 a2 = *(const f16x8*)(ab + 32 * A_STRIDE);
        f16x8 a3 = *(const f16x8*)(ab + 48 * A_STRIDE);
        acc[0][0] = __builtin_amdgcn_mfma_f32_16x16x32_f16(a0, b0, acc[0][0], 0, 0, 0);
        acc[0][1] = __builtin_amdgcn_mfma_f32_16x16x32_f16(a0, b1, acc[0][1], 0, 0, 0);
        acc[0][2] = __builtin_amdgcn_mfma_f32_16x16x32_f16(a0, b2, acc[0][2], 0, 0, 0);
        acc[1][0] = __builtin_amdgcn_mfma_f32_16x16x32_f16(a1, b0, acc[1][0], 0, 0, 0);
        acc[1][1] = __builtin_amdgcn_mfma_f32_16x16x32_f16(a1, b1, acc[1][1], 0, 0, 0);
        acc[1][2] = __builtin_amdgcn_mfma_f32_16x16x32_f16(a1, b2, acc[1][2], 0, 0, 0);
        acc[2][0] = __builtin_amdgcn_mfma_f32_16x16x32_f16(a2, b0, acc[2][0], 0, 0, 0);
        acc[2][1] = __builtin_amdgcn_mfma_f32_16x16x32_f16(a2, b1, acc[2][1], 0, 0, 0);
        acc[2][2] = __builtin_amdgcn_mfma_f32_16x16x32_f16(a2, b2, acc[2][2], 0, 0, 0);
        acc[3][0] = __builtin_amdgcn_mfma_f32_16x16x32_f16(a3, b0, acc[3][0], 0, 0, 0);
        acc[3][1] = __builtin_amdgcn_mfma_f32_16x16x32_f16(a3, b1, acc[3][1], 0, 0, 0);
        acc[3][2] = __builtin_amdgcn_mfma_f32_16x16x32_f16(a3, b2, acc[3][2], 0, 0, 0);

        __syncthreads();   // barrier1: all waves done reading B[kc]; pa drained

        if (has) {
            // stage B[kc+1] into the (now free) buffer — L2-hot, linear copy
            const char* g = (const char*)Wt + (size_t)(kc + 1) * CHUNK_B;
            #pragma unroll
            for (int s = 0; s < 3; ++s) {
                int idx = wave * 3 + s;
                stage16(g + idx * 1024 + lane * 16, smem + LDS_BB + idx * 1024);
            }
            // write-late: next A slice fp16 into resident A (disjoint k-slice), swizzled
            if (tid < 512) {
                int r = tid >> 3;
                f16x4 v;
                v[0] = (_Float16)pa[0]; v[1] = (_Float16)pa[1];
                v[2] = (_Float16)pa[2]; v[3] = (_Float16)pa[3];
                *(f16x4*)(smem + LDS_A + r * A_STRIDE
                          + (((kc + 1) * 64 + (tid & 7) * 8) ^ ASWZ(r))) = v;
            }
        }
        __syncthreads();   // barrier2: B[kc+1] + A[kc+1] visible
    }

    // ---- epilogue: per-wave col-partial scores ----
    float pr[4][4];
    #pragma unroll
    for (int rt = 0; rt < 4; ++rt)
        #pragma unroll
        for (int r = 0; r < 4; ++r) pr[rt][r] = 0.f;

    #pragma unroll
    for (int ct = 0; ct < 3; ++ct) {
        int col = wave * 48 + ct * 16 + l15;
        float bj = bias_s[col];
        float vj = v_s[col];
        #pragma unroll
        for (int rt = 0; rt < 4; ++rt)
            #pragma unroll
            for (int r = 0; r < 4; ++r)
                pr[rt][r] = fmaf(vj, tanh_fast(acc[rt][ct][r] + bj), pr[rt][r]);
    }
    #pragma unroll
    for (int rt = 0; rt < 4; ++rt)
        #pragma unroll
        for (int r = 0; r < 4; ++r) {
            float x = pr[rt][r];
            x += __shfl_xor(x, 1);
            x += __shfl_xor(x, 2);
            x += __shfl_xor(x, 4);
            x += __shfl_xor(x, 8);
            if (l15 == 0) s_red[wave * 64 + rt * 16 + lhi * 4 + r] = x;
        }
    __syncthreads();

    // rows: sum 16 col-group partials, exp, block Z
    if (tid < 64) {
        float s = 0.f;
        #pragma unroll
        for (int w = 0; w < 16; ++w) s += s_red[w * 64 + tid];
        float e = __expf(s);            // |s| <= ||v||_1 ~ 61: no overflow
        e_lds[tid] = e;
        float tot = e;
        tot += __shfl_xor(tot, 1);
        tot += __shfl_xor(tot, 2);
        tot += __shfl_xor(tot, 4);
        tot += __shfl_xor(tot, 8);
        tot += __shfl_xor(tot, 16);
        tot += __shfl_xor(tot, 32);
        if (tid == 0) atomicAdd(Z, tot);
    }
    __syncthreads();

    // ---- fused weighted sum from resident A (h read from HBM exactly once), swizzled reads ----
    if (tid < HDIM) {
        float s = 0.f;
        #pragma unroll 8
        for (int i = 0; i < BM; ++i) {
            const _Float16* ap = (const _Float16*)(smem + LDS_A + i * A_STRIDE
                                                   + ((tid * 2) ^ ASWZ(i)));
            s += e_lds[i] * (float)(*ap);
        }
        if (use_part) part[(size_t)blockIdx.x * HDIM + tid] = s;
        else          atomicAdd(accbuf + tid, s);
    }
}

// ---------------- finalize stage 1: sum 2048 parts in 16 groups of 128 ----------------
__global__ __launch_bounds__(128) void fin1_kernel(
    const float* __restrict__ part, float* __restrict__ part2) {
    const int g  = blockIdx.x / 6;           // group 0..15
    const int cb = blockIdx.x % 6;
    const int col = cb * 128 + threadIdx.x;
    float s = 0.f;
    #pragma unroll 8
    for (int p = g * 128; p < (g + 1) * 128; ++p) s += part[(size_t)p * HDIM + col];
    part2[g * HDIM + col] = s;
}

// ---------------- finalize stage 2: out[j] = sum_g src[g][j] / Z ----------------
__global__ __launch_bounds__(128) void fin2_kernel(
    const float* __restrict__ src, const float* __restrict__ Z,
    float* __restrict__ out, int ngroups) {
    const int col = blockIdx.x * 128 + threadIdx.x;
    float s = 0.f;
    for (int g = 0; g < ngroups; ++g) s += src[g * HDIM + col];
    out[col] = s / (*Z);
}

extern "C" void kernel_launch(void* const* d_in, const int* in_sizes, int n_in,
                              void* d_out, int out_size, void* d_ws, size_t ws_size,
                              hipStream_t stream) {
    const float* h    = (const float*)d_in[0];   // [N, 768]
    const float* W    = (const float*)d_in[1];   // [768, 768]
    const float* bias = (const float*)d_in[2];   // [768]
    const float* vv   = (const float*)d_in[3];   // [1, 768]
    float* out = (float*)d_out;                  // [1, 768] fp32

    const int n = in_sizes[0] / HDIM;            // 131072

    char* ws = (char*)d_ws;
    _Float16* Wt  = (_Float16*)(ws + WS_WT);
    float* Z      = (float*)(ws + WS_Z);
    float* part   = (float*)(ws + WS_PART);
    float* part2  = (float*)(ws + WS_PART2);
    float* accbuf = (float*)(ws + WS_PART);      // small-ws fallback accumulator

    const int use_part = (ws_size >= (size_t)WS_NEED) ? 1 : 0;

    hipFuncSetAttribute((const void*)score_fused_kernel,
                        hipFuncAttributeMaxDynamicSharedMemorySize, LDS_TOTAL);

    // 1) W -> fp16 swizzled chunks; zero Z (+acc)
    prep_kernel<<<72, 1024, 0, stream>>>(W, Wt, Z, accbuf);

    // 2) fused score + exp + weighted-sum partials
    score_fused_kernel<<<n / BM, 1024, LDS_TOTAL, stream>>>(
        h, Wt, bias, vv, part, accbuf, Z, use_part);

    // 3) reduce partials
    if (use_part) {
        fin1_kernel<<<96, 128, 0, stream>>>(part, part2);
        fin2_kernel<<<HDIM / 128, 128, 0, stream>>>(part2, Z, out, 16);
    } else {
        fin2_kernel<<<HDIM / 128, 128, 0, stream>>>(accbuf, Z, out, 1);
    }
}

// Round 11
// 288.646 us; speedup vs baseline: 1.2490x; 1.1388x over previous
//
#include <hip/hip_runtime.h>

#define HDIM 768
#define BM 64                 // rows per block
#define NCHUNK 24             // K chunks of 32
#define CHALF 24576           // halves per Wt chunk (768 cols * 32 k)
#define A_STRIDE 1536         // bytes per A row in LDS
#define ASWZ(row) (((row) & 7) << 4)   // 16B-slot XOR involution (write+read sides)

typedef _Float16 f16x8 __attribute__((ext_vector_type(8)));
typedef _Float16 f16x4 __attribute__((ext_vector_type(4)));
typedef float f32x4 __attribute__((ext_vector_type(4)));

// ---- LDS layout (bytes), dynamic: 108800 ----
#define LDS_A     0            // A resident: [64][1536B] = 98304
#define LDS_BIAS  98304        // 768 f32
#define LDS_V     101376       // 768 f32
#define LDS_SRED  104448       // [16][64] f32 = 4096
#define LDS_E     108544       // 64 f32
#define LDS_TOTAL 108800

// ---- workspace layout (bytes) ----
#define WS_WT    0             // 768*768*2 = 1179648 (fp16 W, chunked [kc][col][32k], linear)
#define WS_Z     1179648       // 4 (+pad)
#define WS_PART  1179712       // 2048*768*4 = 6291456
#define WS_PART2 7471168       // 16*768*4 = 49152
#define WS_NEED  (WS_PART2 + 49152)

__device__ __forceinline__ float tanh_fast(float z) {
    float e2 = __expf(2.0f * z);
    return 1.0f - 2.0f / (e2 + 1.0f);   // inf-safe at both extremes
}

__device__ __forceinline__ f16x8 cvt8(f32x4 x0, f32x4 x1) {
    f16x8 f;
    f[0] = (_Float16)x0[0]; f[1] = (_Float16)x0[1];
    f[2] = (_Float16)x0[2]; f[3] = (_Float16)x0[3];
    f[4] = (_Float16)x1[0]; f[5] = (_Float16)x1[1];
    f[6] = (_Float16)x1[2]; f[7] = (_Float16)x1[3];
    return f;
}

// ---------------- kernel 1: W -> fp16 chunks [kc][col][32k] (linear); zero Z + acc ----------------
__global__ __launch_bounds__(1024) void prep_kernel(
    const float* __restrict__ W, _Float16* __restrict__ Wt,
    float* __restrict__ Z, float* __restrict__ accbuf) {
    int idx = blockIdx.x * 1024 + threadIdx.x;      // 73728 groups: 768 c x 24 kc x 4 q
    if (idx < 73728) {
        int c  = idx / 96;
        int r  = idx - c * 96;
        int kc = r >> 2;
        int q  = r & 3;
        const float* src = W + c * HDIM + kc * 32 + q * 8;
        f16x8 v = cvt8(*(const f32x4*)src, *(const f32x4*)(src + 4));
        *(f16x8*)(Wt + (size_t)kc * CHALF + c * 32 + q * 8) = v;
    }
    if (idx < HDIM) accbuf[idx] = 0.0f;
    if (idx == 0) *Z = 0.0f;
}

// ---------------- kernel 2: fused GEMM + tanh + v-dot + exp + weighted sum ----------------
// 1024 threads (16 waves), BM=64 rows, grid 2048, 1 block/CU (106KB LDS).
// A resident fp16 in LDS (the only LDS traffic); B fragments read DIRECTLY from L2 into a
// ping-pong register set, prefetched one chunk ahead (r8-r10's B LDS round-trip deleted:
// it added ~1150 DS-cyc/chunk + a vmcnt-drain barrier on top of the same L2 traffic).
// One raw s_barrier + lgkmcnt(0) per chunk; vmcnt NEVER drained in the loop.
__global__ __launch_bounds__(1024, 4) void score_fused_kernel(
    const float* __restrict__ h, const _Float16* __restrict__ Wt,
    const float* __restrict__ bias, const float* __restrict__ vvec,
    float* __restrict__ part, float* __restrict__ accbuf,
    float* __restrict__ Z, int use_part) {

    extern __shared__ char smem[];
    float* bias_s = (float*)(smem + LDS_BIAS);
    float* v_s    = (float*)(smem + LDS_V);
    float* s_red  = (float*)(smem + LDS_SRED);
    float* e_lds  = (float*)(smem + LDS_E);

    const int tid  = threadIdx.x;
    const int wave = tid >> 6;       // = col-group 0..15
    const int lane = tid & 63;
    const int l15  = lane & 15;
    const int lhi  = lane >> 4;
    const int row0 = blockIdx.x * BM;

    if (tid < HDIM) { bias_s[tid] = bias[tid]; v_s[tid] = vvec[tid]; }

    // per-lane B source: col = wave*48 + ct*16 + l15, k-span lhi*8 (+kc*32 via chunk stride)
    const _Float16* wtp = Wt + (wave * 48 + l15) * 32 + lhi * 8;
    const int aswz = ASWZ(l15);      // rows l15, +16, +32, +48 share row&7

    // prologue: A slice 0 (64 rows x 32k fp32 -> fp16, swizzled write)
    if (tid < 512) {
        int r = tid >> 3, k4 = tid & 7;
        f32x4 x = __builtin_nontemporal_load(
            (const f32x4*)(h + (size_t)(row0 + r) * HDIM + k4 * 4));
        f16x4 v;
        v[0] = (_Float16)x[0]; v[1] = (_Float16)x[1];
        v[2] = (_Float16)x[2]; v[3] = (_Float16)x[3];
        *(f16x4*)(smem + LDS_A + r * A_STRIDE + ((k4 * 8) ^ ASWZ(r))) = v;
    }
    // prologue: pa for A slice 1; B fragments for chunk 0
    f32x4 paA = {0.f, 0.f, 0.f, 0.f}, paB = {0.f, 0.f, 0.f, 0.f};
    if (tid < 512)
        paA = __builtin_nontemporal_load(
            (const f32x4*)(h + (size_t)(row0 + (tid >> 3)) * HDIM + 32 + (tid & 7) * 4));
    f16x8 bA0 = *(const f16x8*)(wtp);
    f16x8 bA1 = *(const f16x8*)(wtp + 512);
    f16x8 bA2 = *(const f16x8*)(wtp + 1024);
    f16x8 bB0, bB1, bB2;
    __syncthreads();   // one full drain: A0 + bias/v staged

    f32x4 acc[4][3];
    #pragma unroll
    for (int rt = 0; rt < 4; ++rt)
        #pragma unroll
        for (int ct = 0; ct < 3; ++ct)
            acc[rt][ct] = (f32x4){0.f, 0.f, 0.f, 0.f};

// chunk KC: compute from BC*, prefetch B(KC+1) into BN*, write A[KC+1] from PAW,
// load PAL = h slice KC+2. Ends with lgkmcnt(0) + raw s_barrier (vmcnt rides across).
#define CHUNK(KC, BC0, BC1, BC2, BN0, BN1, BN2, PAW, PAL)                              \
    {                                                                                   \
        const char* ab = smem + LDS_A + l15 * A_STRIDE + (((KC) * 64 + lhi * 16) ^ aswz); \
        f16x8 a0 = *(const f16x8*)(ab);                                                 \
        f16x8 a1 = *(const f16x8*)(ab + 16 * A_STRIDE);                                 \
        f16x8 a2 = *(const f16x8*)(ab + 32 * A_STRIDE);                                 \
        f16x8 a3 = *(const f16x8*)(ab + 48 * A_STRIDE);                                 \
        if ((KC) + 1 < NCHUNK) {                                                        \
            const _Float16* wp = wtp + (size_t)((KC) + 1) * CHALF;                      \
            BN0 = *(const f16x8*)(wp);                                                  \
            BN1 = *(const f16x8*)(wp + 512);                                            \
            BN2 = *(const f16x8*)(wp + 1024);                                           \
        }                                                                               \
        if ((KC) + 2 < NCHUNK && tid < 512)                                             \
            PAL = __builtin_nontemporal_load(                                           \
                (const f32x4*)(h + (size_t)(row0 + (tid >> 3)) * HDIM                   \
                               + ((KC) + 2) * 32 + (tid & 7) * 4));                     \
        acc[0][0] = __builtin_amdgcn_mfma_f32_16x16x32_f16(a0, BC0, acc[0][0], 0, 0, 0); \
        acc[0][1] = __builtin_amdgcn_mfma_f32_16x16x32_f16(a0, BC1, acc[0][1], 0, 0, 0); \
        acc[0][2] = __builtin_amdgcn_mfma_f32_16x16x32_f16(a0, BC2, acc[0][2], 0, 0, 0); \
        acc[1][0] = __builtin_amdgcn_mfma_f32_16x16x32_f16(a1, BC0, acc[1][0], 0, 0, 0); \
        acc[1][1] = __builtin_amdgcn_mfma_f32_16x16x32_f16(a1, BC1, acc[1][1], 0, 0, 0); \
        acc[1][2] = __builtin_amdgcn_mfma_f32_16x16x32_f16(a1, BC2, acc[1][2], 0, 0, 0); \
        acc[2][0] = __builtin_amdgcn_mfma_f32_16x16x32_f16(a2, BC0, acc[2][0], 0, 0, 0); \
        acc[2][1] = __builtin_amdgcn_mfma_f32_16x16x32_f16(a2, BC1, acc[2][1], 0, 0, 0); \
        acc[2][2] = __builtin_amdgcn_mfma_f32_16x16x32_f16(a2, BC2, acc[2][2], 0, 0, 0); \
        acc[3][0] = __builtin_amdgcn_mfma_f32_16x16x32_f16(a3, BC0, acc[3][0], 0, 0, 0); \
        acc[3][1] = __builtin_amdgcn_mfma_f32_16x16x32_f16(a3, BC1, acc[3][1], 0, 0, 0); \
        acc[3][2] = __builtin_amdgcn_mfma_f32_16x16x32_f16(a3, BC2, acc[3][2], 0, 0, 0); \
        if ((KC) + 1 < NCHUNK && tid < 512) {                                           \
            int r_ = tid >> 3;                                                          \
            f16x4 v_;                                                                   \
            v_[0] = (_Float16)PAW[0]; v_[1] = (_Float16)PAW[1];                         \
            v_[2] = (_Float16)PAW[2]; v_[3] = (_Float16)PAW[3];                         \
            *(f16x4*)(smem + LDS_A + r_ * A_STRIDE                                      \
                      + ((((KC) + 1) * 64 + (tid & 7) * 8) ^ ASWZ(r_))) = v_;           \
        }                                                                               \
        asm volatile("s_waitcnt lgkmcnt(0)" ::: "memory");                              \
        __builtin_amdgcn_s_barrier();                                                   \
    }

    for (int k2 = 0; k2 < NCHUNK; k2 += 2) {
        CHUNK(k2,     bA0, bA1, bA2, bB0, bB1, bB2, paA, paB)
        CHUNK(k2 + 1, bB0, bB1, bB2, bA0, bA1, bA2, paB, paA)
    }
#undef CHUNK

    __syncthreads();

    // ---- epilogue: per-wave col-partial scores ----
    float pr[4][4];
    #pragma unroll
    for (int rt = 0; rt < 4; ++rt)
        #pragma unroll
        for (int r = 0; r < 4; ++r) pr[rt][r] = 0.f;

    #pragma unroll
    for (int ct = 0; ct < 3; ++ct) {
        int col = wave * 48 + ct * 16 + l15;
        float bj = bias_s[col];
        float vj = v_s[col];
        #pragma unroll
        for (int rt = 0; rt < 4; ++rt)
            #pragma unroll
            for (int r = 0; r < 4; ++r)
                pr[rt][r] = fmaf(vj, tanh_fast(acc[rt][ct][r] + bj), pr[rt][r]);
    }
    #pragma unroll
    for (int rt = 0; rt < 4; ++rt)
        #pragma unroll
        for (int r = 0; r < 4; ++r) {
            float x = pr[rt][r];
            x += __shfl_xor(x, 1);
            x += __shfl_xor(x, 2);
            x += __shfl_xor(x, 4);
            x += __shfl_xor(x, 8);
            if (l15 == 0) s_red[wave * 64 + rt * 16 + lhi * 4 + r] = x;
        }
    __syncthreads();

    // rows: sum 16 col-group partials, exp, block Z
    if (tid < 64) {
        float s = 0.f;
        #pragma unroll
        for (int w = 0; w < 16; ++w) s += s_red[w * 64 + tid];
        float e = __expf(s);            // |s| <= ||v||_1 ~ 61: no overflow
        e_lds[tid] = e;
        float tot = e;
        tot += __shfl_xor(tot, 1);
        tot += __shfl_xor(tot, 2);
        tot += __shfl_xor(tot, 4);
        tot += __shfl_xor(tot, 8);
        tot += __shfl_xor(tot, 16);
        tot += __shfl_xor(tot, 32);
        if (tid == 0) atomicAdd(Z, tot);
    }
    __syncthreads();

    // ---- fused weighted sum from resident A (h read from HBM exactly once) ----
    if (tid < HDIM) {
        float s = 0.f;
        #pragma unroll 8
        for (int i = 0; i < BM; ++i) {
            const _Float16* ap = (const _Float16*)(smem + LDS_A + i * A_STRIDE
                                                   + ((tid * 2) ^ ASWZ(i)));
            s += e_lds[i] * (float)(*ap);
        }
        if (use_part) part[(size_t)blockIdx.x * HDIM + tid] = s;
        else          atomicAdd(accbuf + tid, s);
    }
}

// ---------------- finalize stage 1: sum 2048 parts in 16 groups of 128 ----------------
__global__ __launch_bounds__(128) void fin1_kernel(
    const float* __restrict__ part, float* __restrict__ part2) {
    const int g  = blockIdx.x / 6;           // group 0..15
    const int cb = blockIdx.x % 6;
    const int col = cb * 128 + threadIdx.x;
    float s = 0.f;
    #pragma unroll 8
    for (int p = g * 128; p < (g + 1) * 128; ++p) s += part[(size_t)p * HDIM + col];
    part2[g * HDIM + col] = s;
}

// ---------------- finalize stage 2: out[j] = sum_g src[g][j] / Z ----------------
__global__ __launch_bounds__(128) void fin2_kernel(
    const float* __restrict__ src, const float* __restrict__ Z,
    float* __restrict__ out, int ngroups) {
    const int col = blockIdx.x * 128 + threadIdx.x;
    float s = 0.f;
    for (int g = 0; g < ngroups; ++g) s += src[g * HDIM + col];
    out[col] = s / (*Z);
}

extern "C" void kernel_launch(void* const* d_in, const int* in_sizes, int n_in,
                              void* d_out, int out_size, void* d_ws, size_t ws_size,
                              hipStream_t stream) {
    const float* h    = (const float*)d_in[0];   // [N, 768]
    const float* W    = (const float*)d_in[1];   // [768, 768]
    const float* bias = (const float*)d_in[2];   // [768]
    const float* vv   = (const float*)d_in[3];   // [1, 768]
    float* out = (float*)d_out;                  // [1, 768] fp32

    const int n = in_sizes[0] / HDIM;            // 131072

    char* ws = (char*)d_ws;
    _Float16* Wt  = (_Float16*)(ws + WS_WT);
    float* Z      = (float*)(ws + WS_Z);
    float* part   = (float*)(ws + WS_PART);
    float* part2  = (float*)(ws + WS_PART2);
    float* accbuf = (float*)(ws + WS_PART);      // small-ws fallback accumulator

    const int use_part = (ws_size >= (size_t)WS_NEED) ? 1 : 0;

    hipFuncSetAttribute((const void*)score_fused_kernel,
                        hipFuncAttributeMaxDynamicSharedMemorySize, LDS_TOTAL);

    // 1) W -> fp16 chunks; zero Z (+acc)
    prep_kernel<<<72, 1024, 0, stream>>>(W, Wt, Z, accbuf);

    // 2) fused score + exp + weighted-sum partials
    score_fused_kernel<<<n / BM, 1024, LDS_TOTAL, stream>>>(
        h, Wt, bias, vv, part, accbuf, Z, use_part);

    // 3) reduce partials
    if (use_part) {
        fin1_kernel<<<96, 128, 0, stream>>>(part, part2);
        fin2_kernel<<<HDIM / 128, 128, 0, stream>>>(part2, Z, out, 16);
    } else {
        fin2_kernel<<<HDIM / 128, 128, 0, stream>>>(accbuf, Z, out, 1);
    }
}